// Round 2
// baseline (296.532 us; speedup 1.0000x reference)
//
#include <hip/hip_runtime.h>
#include <hip/hip_fp16.h>

// Arena-contiguous scatter/gather:
//   zero  : zero bucket counters (and accSlots on first chunk).
//   count : per-block LDS histogram of node buckets -> global padded counters.
//   scan  : 1 block scans 1024 counters -> base[NB+1]; counters become cursors.
//   fill  : tile = 4096 elems; compute forces, LDS bucket-sort (2 stages),
//           reserve per-(tile,bucket) extent via one fetch_add on the bucket
//           cursor, flush coalesced into the bucket's CONTIGUOUS arena range.
//   accum : block = bucket; reads its arena range as a dense coalesced stream
//           into an LDS fp32 tile; fused masked loss on last chunk.
//   final : 1 wave reduces 64 slot pairs, divides, writes out[0].
// Records: 8B {fx16,fy16 | local16,fz16}. Streaming reads use nontemporal
// hints so the 12 MB pred gather target stays L3-resident.
// Ladder: K=1 (no partial) preferred; K=2 fp32/fp16 partial fallback.

#define SPAN   1024
#define NBMAX  1024
#define CURP   16            // ints per padded counter slot (64 B line)
#define FTH    1024          // fill threads
#define FBE    4096          // elems per fill tile
#define ATH    512           // accum threads
#define CB     256           // count blocks

struct F3 { float x, y, z; };

__device__ __forceinline__ uint2 packrec(float fx, float fy, float fz, int local) {
    unsigned short hx = __half_as_ushort(__float2half(fx));
    unsigned short hy = __half_as_ushort(__float2half(fy));
    unsigned short hz = __half_as_ushort(__float2half(fz));
    return make_uint2(((unsigned)hy << 16) | hx, ((unsigned)local << 16) | hz);
}

// 1024-thread inclusive scan. Call sites must be separated by __syncthreads().
__device__ __forceinline__ int block_incl_scan(int v, int* wsum, int lane, int wv) {
    #pragma unroll
    for (int off = 1; off < 64; off <<= 1) {
        int t = __shfl_up(v, off, 64);
        if (lane >= off) v += t;
    }
    if (lane == 63) wsum[wv] = v;
    __syncthreads();
    if (wv == 0) {
        int w = (lane < 16) ? wsum[lane] : 0;
        #pragma unroll
        for (int off = 1; off < 16; off <<= 1) {
            int t = __shfl_up(w, off, 64);
            if (lane >= off) w += t;
        }
        if (lane < 16) wsum[lane] = w;
    }
    __syncthreads();
    return v + ((wv > 0) ? wsum[wv - 1] : 0);
}

__global__ void __launch_bounds__(1024)
zero_kernel(int* __restrict__ p, int n) {
    int i = blockIdx.x * 1024 + threadIdx.x;
    if (i < n) p[i] = 0;
}

__global__ void __launch_bounds__(1024)
count_kernel(const long long* __restrict__ conn, int* __restrict__ cnt,
             int cs, int ce) {
    __shared__ int h[NBMAX];
    int tid = threadIdx.x;
    h[tid] = 0;
    __syncthreads();
    int stride = gridDim.x * 1024;
    for (int e = cs + blockIdx.x * 1024 + tid; e < ce; e += stride) {
        long long v = __builtin_nontemporal_load(conn + e);
        int na = (int)(unsigned)((unsigned long long)v & 0xFFFFFFFFull);
        int nb = (int)(unsigned)((unsigned long long)v >> 32);
        atomicAdd(&h[na >> 10], 1);
        atomicAdd(&h[nb >> 10], 1);
    }
    __syncthreads();
    int c = h[tid];
    if (c) atomicAdd(&cnt[tid * CURP], c);
}

__global__ void __launch_bounds__(1024)
scan_kernel(int* __restrict__ cnt, int* __restrict__ base) {
    __shared__ int wsum[16];
    int tid = threadIdx.x, lane = tid & 63, wv = tid >> 6;
    int c = cnt[tid * CURP];
    int incl = block_incl_scan(c, wsum, lane, wv);
    base[tid + 1] = incl;
    if (tid == 0) base[0] = 0;
    cnt[tid * CURP] = incl - c;   // cursor = exclusive start
}

__global__ void __launch_bounds__(1024)
fill_kernel(const long long* __restrict__ conn,
            const F3*  __restrict__ pred,
            const float* __restrict__ u_c,
            const float* __restrict__ theta_c,
            const float* __restrict__ len,
            const float* __restrict__ pE,
            const float* __restrict__ pA,
            const float* __restrict__ pI,
            const float* __restrict__ dir,
            uint2* __restrict__ arena,
            int* __restrict__ cursor,
            int cs, int ce) {
    __shared__ uint2          slab[FBE];   // 32KB: one stage (2048 elems -> 4096 recs)
    __shared__ unsigned short sbk [FBE];   // 8KB
    __shared__ int hist0[NBMAX];
    __shared__ int hist1[NBMAX];
    __shared__ int sc   [NBMAX];
    __shared__ int astart[NBMAX];
    __shared__ int wsum [16];

    int tid = threadIdx.x, lane = tid & 63, wv = tid >> 6;

    hist0[tid] = 0;
    hist1[tid] = 0;
    __syncthreads();

    float uc = u_c[0];
    float tc = theta_c[0];
    int bs = cs + blockIdx.x * FBE;
    int be = bs + FBE; if (be > ce) be = ce;

    unsigned sv[8];   // (rank<<10)|bucket ; 0xFFFFFFFF = none
    uint2    rc[8];

    #pragma unroll
    for (int j = 0; j < 4; ++j) {
        int e = bs + j * FTH + tid;
        unsigned sa = 0xFFFFFFFFu, sb = 0xFFFFFFFFu;
        if (e < be) {
            long long cv = __builtin_nontemporal_load(conn + e);
            int na = (int)(unsigned)((unsigned long long)cv & 0xFFFFFFFFull);
            int nb = (int)(unsigned)((unsigned long long)cv >> 32);

            F3 pa_ = pred[na];            // temporal: keep L3-resident
            F3 pb_ = pred[nb];

            float c  = __builtin_nontemporal_load(&dir[3 * e + 0]);
            float s  = __builtin_nontemporal_load(&dir[3 * e + 2]);
            float L  = __builtin_nontemporal_load(&len[e]);
            float Ee = __builtin_nontemporal_load(&pE[e]);
            float EA = Ee * __builtin_nontemporal_load(&pA[e]);
            float EI = Ee * __builtin_nontemporal_load(&pI[e]);

            float a0 = pa_.x * uc;
            float a1 = pa_.y * uc;
            float a2 = pa_.z * tc;
            float b0 = pb_.x * uc;
            float b1 = pb_.y * uc;
            float b2 = pb_.z * tc;

            float u_A  =  c * a0 + s * a1;
            float w_A  = -s * a0 + c * a1;
            float th_A = -a2;
            float u_B  =  c * b0 + s * b1;
            float w_B  = -s * b0 + c * b1;
            float th_B = -b2;

            float invL  = 1.0f / L;
            float ea_l  = EA * invL;             // AXIAL_WEIGHT = 1.0
            float ei_l  = EI * invL;
            float ei_l2 = ei_l  * invL;
            float ei_l3 = ei_l2 * invL;

            float dw = w_A - w_B;
            float f0 = ea_l * (u_A - u_B);
            float f1 = 12.0f * ei_l3 * dw + 6.0f * ei_l2 * (th_A + th_B);
            float f2 = 6.0f * ei_l2 * dw + 4.0f * ei_l * th_A + 2.0f * ei_l * th_B;
            float f5 = 6.0f * ei_l2 * dw + 2.0f * ei_l * th_A + 4.0f * ei_l * th_B;

            float fA0 = c * f0 - s * f1;
            float fA1 = s * f0 + c * f1;

            int* h = (j < 2) ? hist0 : hist1;

            int bkA = na >> 10;
            int rA  = atomicAdd(&h[bkA], 1);
            sa = ((unsigned)rA << 10) | (unsigned)bkA;
            rc[2 * j + 0] = packrec(fA0, fA1, -f2, na & 1023);

            int bkB = nb >> 10;
            int rB  = atomicAdd(&h[bkB], 1);
            sb = ((unsigned)rB << 10) | (unsigned)bkB;
            rc[2 * j + 1] = packrec(-fA0, -fA1, -f5, nb & 1023);
        }
        sv[2 * j + 0] = sa;
        sv[2 * j + 1] = sb;
    }
    __syncthreads();

    // one arena reservation per (tile,bucket): combined count of both stages
    int h0 = hist0[tid], h1 = hist1[tid];
    int tot = h0 + h1;
    if (tot) astart[tid] = atomicAdd(&cursor[tid * CURP], tot);

    // ---- stage 0 ----
    int i0 = block_incl_scan(h0, wsum, lane, wv);   // internal syncs order astart
    sc[tid] = i0;
    __syncthreads();
    #pragma unroll
    for (int r = 0; r < 4; ++r) {
        unsigned s2 = sv[r];
        if (s2 != 0xFFFFFFFFu) {
            int bk = (int)(s2 & 1023u);
            int rk = (int)(s2 >> 10);
            int slot = sc[bk] - hist0[bk] + rk;
            slab[slot] = rc[r];
            sbk[slot]  = (unsigned short)bk;
        }
    }
    __syncthreads();
    int tot0 = sc[NBMAX - 1];
    for (int i = tid; i < tot0; i += FTH) {
        int bk = sbk[i];
        arena[astart[bk] + (i - (sc[bk] - hist0[bk]))] = slab[i];
    }
    __syncthreads();

    // ---- stage 1 ----
    int i1 = block_incl_scan(h1, wsum, lane, wv);
    sc[tid] = i1;
    __syncthreads();
    #pragma unroll
    for (int r = 4; r < 8; ++r) {
        unsigned s2 = sv[r];
        if (s2 != 0xFFFFFFFFu) {
            int bk = (int)(s2 & 1023u);
            int rk = (int)(s2 >> 10);
            int slot = sc[bk] - hist1[bk] + rk;
            slab[slot] = rc[r];
            sbk[slot]  = (unsigned short)bk;
        }
    }
    __syncthreads();
    int tot1 = sc[NBMAX - 1];
    for (int i = tid; i < tot1; i += FTH) {
        int bk = sbk[i];
        arena[astart[bk] + hist0[bk] + (i - (sc[bk] - hist1[bk]))] = slab[i];
    }
}

__global__ void __launch_bounds__(512)
accum_kernel(const unsigned long long* __restrict__ arena,
             const int* __restrict__ base,
             const float* __restrict__ Fext,
             const float* __restrict__ bcd,
             const float* __restrict__ bcr,
             double* __restrict__ accSlots,
             float* __restrict__ fint32,
             __half* __restrict__ fint16,
             int N, int isFirst, int isLast, int mode) {
    __shared__ float tile[SPAN * 3];
    __shared__ double sn[8], sd[8];

    int tid = threadIdx.x, lane = tid & 63, wv = tid >> 6;
    int b = blockIdx.x;
    int nodeLo = b * SPAN;
    int gBase = nodeLo * 3;
    int gMax  = 3 * N;

    if (isFirst) {
        for (int i = tid; i < SPAN * 3; i += ATH) tile[i] = 0.0f;
    } else if (mode == 1) {
        for (int i = tid; i < SPAN * 3; i += ATH) {
            int g = gBase + i;
            tile[i] = (g < gMax) ? fint32[g] : 0.0f;
        }
    } else {
        for (int i = tid; i < SPAN * 3; i += ATH) {
            int g = gBase + i;
            tile[i] = (g < gMax) ? __half2float(fint16[g]) : 0.0f;
        }
    }
    __syncthreads();

    // dense coalesced replay of this bucket's contiguous arena range
    int s0 = base[b];
    int s1 = base[b + 1];
    for (int i = s0 + tid; i < s1; i += ATH) {
        unsigned long long rv = __builtin_nontemporal_load(arena + i);
        unsigned lo = (unsigned)(rv & 0xFFFFFFFFull);
        unsigned hi = (unsigned)(rv >> 32);
        float fx = __half2float(__ushort_as_half((unsigned short)(lo & 0xFFFFu)));
        float fy = __half2float(__ushort_as_half((unsigned short)(lo >> 16)));
        float fz = __half2float(__ushort_as_half((unsigned short)(hi & 0xFFFFu)));
        int local = (int)(hi >> 16);
        atomicAdd(&tile[local * 3 + 0], fx);
        atomicAdd(&tile[local * 3 + 1], fy);
        atomicAdd(&tile[local * 3 + 2], fz);
    }
    __syncthreads();

    if (!isLast) {
        if (mode == 1) {
            for (int i = tid; i < SPAN * 3; i += ATH) {
                int g = gBase + i;
                if (g < gMax) fint32[g] = tile[i];
            }
        } else {
            for (int i = tid; i < SPAN * 3; i += ATH) {
                int g = gBase + i;
                if (g < gMax) fint16[g] = __float2half(tile[i]);
            }
        }
        return;
    }

    // fused masked loss over this bucket's node range
    int spanCnt = N - nodeLo;
    if (spanCnt > SPAN) spanCnt = SPAN;

    double num = 0.0, den = 0.0;
    for (int l = tid; l < spanCnt; l += ATH) {
        int n = nodeLo + l;
        float md = 1.0f - __builtin_nontemporal_load(&bcd[n]);
        float mr = 1.0f - __builtin_nontemporal_load(&bcr[n]);
        float e0 = __builtin_nontemporal_load(&Fext[3 * n + 0]);
        float e1 = __builtin_nontemporal_load(&Fext[3 * n + 1]);
        float e2 = __builtin_nontemporal_load(&Fext[3 * n + 2]);
        float r0 = (tile[l * 3 + 0] - e0) * md;
        float r1 = (tile[l * 3 + 1] - e1) * md;
        float r2 = (tile[l * 3 + 2] - e2) * mr;
        float g0 = e0 * md;
        float g1 = e1 * md;
        float g2 = e2 * mr;
        num += (double)r0 * r0 + (double)r1 * r1 + (double)r2 * r2;
        den += (double)g0 * g0 + (double)g1 * g1 + (double)g2 * g2;
    }
    #pragma unroll
    for (int off = 32; off > 0; off >>= 1) {
        num += __shfl_down(num, off, 64);
        den += __shfl_down(den, off, 64);
    }
    if (lane == 0) { sn[wv] = num; sd[wv] = den; }
    __syncthreads();
    if (tid == 0) {
        double tn = 0.0, td = 0.0;
        #pragma unroll
        for (int w = 0; w < 8; ++w) { tn += sn[w]; td += sd[w]; }
        double* slot = accSlots + (size_t)(b & 63) * 8;
        atomicAdd(&slot[0], tn);
        atomicAdd(&slot[1], td);
    }
}

__global__ void final_kernel(const double* __restrict__ accSlots,
                             float* __restrict__ out) {
    int t = threadIdx.x;   // 64 threads
    double n = accSlots[t * 8 + 0];
    double d = accSlots[t * 8 + 1];
    #pragma unroll
    for (int off = 32; off > 0; off >>= 1) {
        n += __shfl_down(n, off, 64);
        d += __shfl_down(d, off, 64);
    }
    if (t == 0) {
        if (d < 1e-30) d = 1e-30;
        out[0] = (float)(n / d);
    }
}

static inline size_t align256(size_t x) { return (x + 255) & ~(size_t)255; }

extern "C" void kernel_launch(void* const* d_in, const int* in_sizes, int n_in,
                              void* d_out, int out_size, void* d_ws, size_t ws_size,
                              hipStream_t stream) {
    const F3*    pred    = (const F3*)d_in[0];
    const float* u_c     = (const float*)d_in[1];
    const float* theta_c = (const float*)d_in[2];
    const float* len     = (const float*)d_in[3];
    const float* pE      = (const float*)d_in[4];
    const float* pA      = (const float*)d_in[5];
    const float* pI      = (const float*)d_in[6];
    const float* dir     = (const float*)d_in[7];
    const float* Fext    = (const float*)d_in[8];
    const float* bcd     = (const float*)d_in[9];
    const float* bcr     = (const float*)d_in[10];
    const long long* conn = (const long long*)d_in[11];

    int N = in_sizes[0] / 3;
    int E = in_sizes[3];
    int NB = (N + SPAN - 1) / SPAN;   // must be <= NBMAX

    // Workspace layout:
    //   0      accSlots   4096 B (64 slots * 64B)
    //   4096   cnt/cursor NBMAX*CURP*4 = 65536 B (padded, one counter/line)
    //   69632  base       (NBMAX+1)*4 B
    //   oFint  fp32/fp16 partial (K>1 only)
    //   oArena arena: 2*chunkElems records * 8 B (exact, no padding)
    size_t oCnt  = 4096;
    size_t oBase = oCnt + (size_t)NBMAX * CURP * 4;          // 69632
    size_t oFint0 = align256(oBase + 4 * (NBMAX + 1));        // 73984

    const int cfgK[6] = {1, 2, 2, 4, 4, 8};
    const int cfgM[6] = {0, 1, 2, 1, 2, 2};
    int K = 8, mode = 2;
    size_t oF = oFint0, oA = oFint0;
    for (int t = 0; t < 6; ++t) {
        int Kc = cfgK[t], Mc = cfgM[t];
        size_t chunkE = (size_t)(E + Kc - 1) / Kc;
        size_t fsz = (Kc > 1) ? (size_t)3 * N * (Mc == 1 ? 4 : 2) : 0;
        size_t oAt = align256(oFint0 + fsz);
        size_t need = oAt + 2 * chunkE * 8;
        if (need <= ws_size || t == 5) {
            K = Kc; mode = Mc; oF = oFint0; oA = oAt;
            if (need <= ws_size) break;
        }
    }

    int chunkElems = (E + K - 1) / K;

    double*             accSlots = (double*)d_ws;
    int*                cnt      = (int*)((char*)d_ws + oCnt);
    int*                base     = (int*)((char*)d_ws + oBase);
    float*              fint32   = (float*)((char*)d_ws + oF);
    __half*             fint16   = (__half*)((char*)d_ws + oF);
    uint2*              arena    = (uint2*)((char*)d_ws + oA);
    unsigned long long* arenaLL  = (unsigned long long*)arena;

    int zeroWordsAll = (int)(oBase / 4);            // accSlots + cnt
    int zeroWordsCnt = (int)((oBase - oCnt) / 4);   // cnt only

    for (int c = 0; c < K; ++c) {
        int cs = c * chunkElems;
        if (cs >= E) break;
        int ce = cs + chunkElems;
        if (ce > E) ce = E;
        int NT = (ce - cs + FBE - 1) / FBE;

        if (c == 0) {
            zero_kernel<<<(zeroWordsAll + 1023) / 1024, 1024, 0, stream>>>(
                (int*)d_ws, zeroWordsAll);
        } else {
            zero_kernel<<<(zeroWordsCnt + 1023) / 1024, 1024, 0, stream>>>(
                cnt, zeroWordsCnt);
        }
        count_kernel<<<CB, 1024, 0, stream>>>(conn, cnt, cs, ce);
        scan_kernel<<<1, 1024, 0, stream>>>(cnt, base);
        fill_kernel<<<NT, FTH, 0, stream>>>(
            conn, pred, u_c, theta_c, len, pE, pA, pI, dir,
            arena, cnt, cs, ce);

        int isFirst = (c == 0);
        int isLast  = (ce == E);
        accum_kernel<<<NB, ATH, 0, stream>>>(
            arenaLL, base, Fext, bcd, bcr, accSlots,
            fint32, fint16, N, isFirst, isLast, mode);
    }

    final_kernel<<<1, 64, 0, stream>>>(accSlots, (float*)d_out);
}

// Round 3
// 294.544 us; speedup vs baseline: 1.0068x; 1.0068x over previous
//
#include <hip/hip_runtime.h>
#include <hip/hip_fp16.h>

// Arena-contiguous scatter/gather, v3 (atomic-free pre-pass):
//   count : 96 blocks; per-block LDS histogram of node buckets -> plain-store
//           row cntMat[blk][1024] (aliased into arena region, no zeroing, no
//           global atomics).
//   scan  : 1 block; column-reduce 96 rows (coalesced), block scan ->
//           base[NB+1]; init padded cursors; zero accSlots on first chunk.
//   fill  : tile = 4096 elems; compute forces, LDS bucket-sort (2 stages),
//           reserve per-(tile,bucket) extent via one fetch_add on the bucket
//           cursor, flush coalesced into the bucket's CONTIGUOUS arena range.
//   accum : block = bucket; reads its arena range as a dense coalesced stream
//           into an LDS fp32 tile; fused masked loss on last chunk.
//   final : 1 wave reduces 64 slot pairs, divides, writes out[0].
// Records: 8B {fx16,fy16 | local16,fz16}. K=1 footprint = 73984 B + 32 MB.

#define SPAN   1024
#define NBMAX  1024
#define CURP   16            // ints per padded cursor slot (64 B line)
#define FTH    1024          // fill threads
#define FBE    4096          // elems per fill tile
#define ATH    512           // accum threads
#define CB     96            // count blocks (plain-store rows)

struct F3 { float x, y, z; };

__device__ __forceinline__ uint2 packrec(float fx, float fy, float fz, int local) {
    unsigned short hx = __half_as_ushort(__float2half(fx));
    unsigned short hy = __half_as_ushort(__float2half(fy));
    unsigned short hz = __half_as_ushort(__float2half(fz));
    return make_uint2(((unsigned)hy << 16) | hx, ((unsigned)local << 16) | hz);
}

// 1024-thread inclusive scan. Call sites must be separated by __syncthreads().
__device__ __forceinline__ int block_incl_scan(int v, int* wsum, int lane, int wv) {
    #pragma unroll
    for (int off = 1; off < 64; off <<= 1) {
        int t = __shfl_up(v, off, 64);
        if (lane >= off) v += t;
    }
    if (lane == 63) wsum[wv] = v;
    __syncthreads();
    if (wv == 0) {
        int w = (lane < 16) ? wsum[lane] : 0;
        #pragma unroll
        for (int off = 1; off < 16; off <<= 1) {
            int t = __shfl_up(w, off, 64);
            if (lane >= off) w += t;
        }
        if (lane < 16) wsum[lane] = w;
    }
    __syncthreads();
    return v + ((wv > 0) ? wsum[wv - 1] : 0);
}

__global__ void __launch_bounds__(1024)
count_kernel(const long long* __restrict__ conn, int* __restrict__ rows,
             int cs, int ce) {
    __shared__ int h[NBMAX];
    int tid = threadIdx.x;
    h[tid] = 0;
    __syncthreads();
    int stride = gridDim.x * 1024;
    for (int e = cs + blockIdx.x * 1024 + tid; e < ce; e += stride) {
        long long v = __builtin_nontemporal_load(conn + e);
        int na = (int)(unsigned)((unsigned long long)v & 0xFFFFFFFFull);
        int nb = (int)(unsigned)((unsigned long long)v >> 32);
        atomicAdd(&h[na >> 10], 1);
        atomicAdd(&h[nb >> 10], 1);
    }
    __syncthreads();
    rows[blockIdx.x * NBMAX + tid] = h[tid];   // plain store, no zero needed
}

__global__ void __launch_bounds__(1024)
scan_kernel(const int* __restrict__ rows, int* __restrict__ cursor,
            int* __restrict__ base, double* __restrict__ accSlots,
            int isFirst) {
    __shared__ int wsum[16];
    int tid = threadIdx.x, lane = tid & 63, wv = tid >> 6;
    int c = 0;
    #pragma unroll 4
    for (int r = 0; r < CB; ++r) c += rows[r * NBMAX + tid];  // coalesced cols
    int incl = block_incl_scan(c, wsum, lane, wv);
    base[tid + 1] = incl;
    if (tid == 0) base[0] = 0;
    cursor[tid * CURP] = incl - c;   // cursor = exclusive start
    if (isFirst && tid < 512) accSlots[tid] = 0.0;
}

__global__ void __launch_bounds__(1024)
fill_kernel(const long long* __restrict__ conn,
            const F3*  __restrict__ pred,
            const float* __restrict__ u_c,
            const float* __restrict__ theta_c,
            const float* __restrict__ len,
            const float* __restrict__ pE,
            const float* __restrict__ pA,
            const float* __restrict__ pI,
            const float* __restrict__ dir,
            uint2* __restrict__ arena,
            int* __restrict__ cursor,
            int cs, int ce) {
    __shared__ uint2          slab[FBE];   // 32KB: one stage (2048 elems -> 4096 recs)
    __shared__ unsigned short sbk [FBE];   // 8KB
    __shared__ int hist0[NBMAX];
    __shared__ int hist1[NBMAX];
    __shared__ int sc   [NBMAX];
    __shared__ int astart[NBMAX];
    __shared__ int wsum [16];

    int tid = threadIdx.x, lane = tid & 63, wv = tid >> 6;

    hist0[tid] = 0;
    hist1[tid] = 0;
    __syncthreads();

    float uc = u_c[0];
    float tc = theta_c[0];
    int bs = cs + blockIdx.x * FBE;
    int be = bs + FBE; if (be > ce) be = ce;

    unsigned sv[8];   // (rank<<10)|bucket ; 0xFFFFFFFF = none
    uint2    rc[8];

    #pragma unroll
    for (int j = 0; j < 4; ++j) {
        int e = bs + j * FTH + tid;
        unsigned sa = 0xFFFFFFFFu, sb = 0xFFFFFFFFu;
        if (e < be) {
            long long cv = __builtin_nontemporal_load(conn + e);
            int na = (int)(unsigned)((unsigned long long)cv & 0xFFFFFFFFull);
            int nb = (int)(unsigned)((unsigned long long)cv >> 32);

            F3 pa_ = pred[na];            // temporal: keep L3-resident
            F3 pb_ = pred[nb];

            float c  = __builtin_nontemporal_load(&dir[3 * e + 0]);
            float s  = __builtin_nontemporal_load(&dir[3 * e + 2]);
            float L  = __builtin_nontemporal_load(&len[e]);
            float Ee = __builtin_nontemporal_load(&pE[e]);
            float EA = Ee * __builtin_nontemporal_load(&pA[e]);
            float EI = Ee * __builtin_nontemporal_load(&pI[e]);

            float a0 = pa_.x * uc;
            float a1 = pa_.y * uc;
            float a2 = pa_.z * tc;
            float b0 = pb_.x * uc;
            float b1 = pb_.y * uc;
            float b2 = pb_.z * tc;

            float u_A  =  c * a0 + s * a1;
            float w_A  = -s * a0 + c * a1;
            float th_A = -a2;
            float u_B  =  c * b0 + s * b1;
            float w_B  = -s * b0 + c * b1;
            float th_B = -b2;

            float invL  = 1.0f / L;
            float ea_l  = EA * invL;             // AXIAL_WEIGHT = 1.0
            float ei_l  = EI * invL;
            float ei_l2 = ei_l  * invL;
            float ei_l3 = ei_l2 * invL;

            float dw = w_A - w_B;
            float f0 = ea_l * (u_A - u_B);
            float f1 = 12.0f * ei_l3 * dw + 6.0f * ei_l2 * (th_A + th_B);
            float f2 = 6.0f * ei_l2 * dw + 4.0f * ei_l * th_A + 2.0f * ei_l * th_B;
            float f5 = 6.0f * ei_l2 * dw + 2.0f * ei_l * th_A + 4.0f * ei_l * th_B;

            float fA0 = c * f0 - s * f1;
            float fA1 = s * f0 + c * f1;

            int* h = (j < 2) ? hist0 : hist1;

            int bkA = na >> 10;
            int rA  = atomicAdd(&h[bkA], 1);
            sa = ((unsigned)rA << 10) | (unsigned)bkA;
            rc[2 * j + 0] = packrec(fA0, fA1, -f2, na & 1023);

            int bkB = nb >> 10;
            int rB  = atomicAdd(&h[bkB], 1);
            sb = ((unsigned)rB << 10) | (unsigned)bkB;
            rc[2 * j + 1] = packrec(-fA0, -fA1, -f5, nb & 1023);
        }
        sv[2 * j + 0] = sa;
        sv[2 * j + 1] = sb;
    }
    __syncthreads();

    // one arena reservation per (tile,bucket): combined count of both stages
    int h0 = hist0[tid], h1 = hist1[tid];
    int tot = h0 + h1;
    if (tot) astart[tid] = atomicAdd(&cursor[tid * CURP], tot);

    // ---- stage 0 ----
    int i0 = block_incl_scan(h0, wsum, lane, wv);   // internal syncs order astart
    sc[tid] = i0;
    __syncthreads();
    #pragma unroll
    for (int r = 0; r < 4; ++r) {
        unsigned s2 = sv[r];
        if (s2 != 0xFFFFFFFFu) {
            int bk = (int)(s2 & 1023u);
            int rk = (int)(s2 >> 10);
            int slot = sc[bk] - hist0[bk] + rk;
            slab[slot] = rc[r];
            sbk[slot]  = (unsigned short)bk;
        }
    }
    __syncthreads();
    int tot0 = sc[NBMAX - 1];
    for (int i = tid; i < tot0; i += FTH) {
        int bk = sbk[i];
        arena[astart[bk] + (i - (sc[bk] - hist0[bk]))] = slab[i];
    }
    __syncthreads();

    // ---- stage 1 ----
    int i1 = block_incl_scan(h1, wsum, lane, wv);
    sc[tid] = i1;
    __syncthreads();
    #pragma unroll
    for (int r = 4; r < 8; ++r) {
        unsigned s2 = sv[r];
        if (s2 != 0xFFFFFFFFu) {
            int bk = (int)(s2 & 1023u);
            int rk = (int)(s2 >> 10);
            int slot = sc[bk] - hist1[bk] + rk;
            slab[slot] = rc[r];
            sbk[slot]  = (unsigned short)bk;
        }
    }
    __syncthreads();
    int tot1 = sc[NBMAX - 1];
    for (int i = tid; i < tot1; i += FTH) {
        int bk = sbk[i];
        arena[astart[bk] + hist0[bk] + (i - (sc[bk] - hist1[bk]))] = slab[i];
    }
}

__global__ void __launch_bounds__(512)
accum_kernel(const unsigned long long* __restrict__ arena,
             const int* __restrict__ base,
             const float* __restrict__ Fext,
             const float* __restrict__ bcd,
             const float* __restrict__ bcr,
             double* __restrict__ accSlots,
             float* __restrict__ fint32,
             __half* __restrict__ fint16,
             int N, int isFirst, int isLast, int mode) {
    __shared__ float tile[SPAN * 3];
    __shared__ double sn[8], sd[8];

    int tid = threadIdx.x, lane = tid & 63, wv = tid >> 6;
    int b = blockIdx.x;
    int nodeLo = b * SPAN;
    int gBase = nodeLo * 3;
    int gMax  = 3 * N;

    if (isFirst) {
        for (int i = tid; i < SPAN * 3; i += ATH) tile[i] = 0.0f;
    } else if (mode == 1) {
        for (int i = tid; i < SPAN * 3; i += ATH) {
            int g = gBase + i;
            tile[i] = (g < gMax) ? fint32[g] : 0.0f;
        }
    } else {
        for (int i = tid; i < SPAN * 3; i += ATH) {
            int g = gBase + i;
            tile[i] = (g < gMax) ? __half2float(fint16[g]) : 0.0f;
        }
    }
    __syncthreads();

    // dense coalesced replay of this bucket's contiguous arena range
    int s0 = base[b];
    int s1 = base[b + 1];
    for (int i = s0 + tid; i < s1; i += ATH) {
        unsigned long long rv = __builtin_nontemporal_load(arena + i);
        unsigned lo = (unsigned)(rv & 0xFFFFFFFFull);
        unsigned hi = (unsigned)(rv >> 32);
        float fx = __half2float(__ushort_as_half((unsigned short)(lo & 0xFFFFu)));
        float fy = __half2float(__ushort_as_half((unsigned short)(lo >> 16)));
        float fz = __half2float(__ushort_as_half((unsigned short)(hi & 0xFFFFu)));
        int local = (int)(hi >> 16);
        atomicAdd(&tile[local * 3 + 0], fx);
        atomicAdd(&tile[local * 3 + 1], fy);
        atomicAdd(&tile[local * 3 + 2], fz);
    }
    __syncthreads();

    if (!isLast) {
        if (mode == 1) {
            for (int i = tid; i < SPAN * 3; i += ATH) {
                int g = gBase + i;
                if (g < gMax) fint32[g] = tile[i];
            }
        } else {
            for (int i = tid; i < SPAN * 3; i += ATH) {
                int g = gBase + i;
                if (g < gMax) fint16[g] = __float2half(tile[i]);
            }
        }
        return;
    }

    // fused masked loss over this bucket's node range
    int spanCnt = N - nodeLo;
    if (spanCnt > SPAN) spanCnt = SPAN;

    double num = 0.0, den = 0.0;
    for (int l = tid; l < spanCnt; l += ATH) {
        int n = nodeLo + l;
        float md = 1.0f - __builtin_nontemporal_load(&bcd[n]);
        float mr = 1.0f - __builtin_nontemporal_load(&bcr[n]);
        float e0 = __builtin_nontemporal_load(&Fext[3 * n + 0]);
        float e1 = __builtin_nontemporal_load(&Fext[3 * n + 1]);
        float e2 = __builtin_nontemporal_load(&Fext[3 * n + 2]);
        float r0 = (tile[l * 3 + 0] - e0) * md;
        float r1 = (tile[l * 3 + 1] - e1) * md;
        float r2 = (tile[l * 3 + 2] - e2) * mr;
        float g0 = e0 * md;
        float g1 = e1 * md;
        float g2 = e2 * mr;
        num += (double)r0 * r0 + (double)r1 * r1 + (double)r2 * r2;
        den += (double)g0 * g0 + (double)g1 * g1 + (double)g2 * g2;
    }
    #pragma unroll
    for (int off = 32; off > 0; off >>= 1) {
        num += __shfl_down(num, off, 64);
        den += __shfl_down(den, off, 64);
    }
    if (lane == 0) { sn[wv] = num; sd[wv] = den; }
    __syncthreads();
    if (tid == 0) {
        double tn = 0.0, td = 0.0;
        #pragma unroll
        for (int w = 0; w < 8; ++w) { tn += sn[w]; td += sd[w]; }
        double* slot = accSlots + (size_t)(b & 63) * 8;
        atomicAdd(&slot[0], tn);
        atomicAdd(&slot[1], td);
    }
}

__global__ void final_kernel(const double* __restrict__ accSlots,
                             float* __restrict__ out) {
    int t = threadIdx.x;   // 64 threads
    double n = accSlots[t * 8 + 0];
    double d = accSlots[t * 8 + 1];
    #pragma unroll
    for (int off = 32; off > 0; off >>= 1) {
        n += __shfl_down(n, off, 64);
        d += __shfl_down(d, off, 64);
    }
    if (t == 0) {
        if (d < 1e-30) d = 1e-30;
        out[0] = (float)(n / d);
    }
}

static inline size_t align256(size_t x) { return (x + 255) & ~(size_t)255; }

extern "C" void kernel_launch(void* const* d_in, const int* in_sizes, int n_in,
                              void* d_out, int out_size, void* d_ws, size_t ws_size,
                              hipStream_t stream) {
    const F3*    pred    = (const F3*)d_in[0];
    const float* u_c     = (const float*)d_in[1];
    const float* theta_c = (const float*)d_in[2];
    const float* len     = (const float*)d_in[3];
    const float* pE      = (const float*)d_in[4];
    const float* pA      = (const float*)d_in[5];
    const float* pI      = (const float*)d_in[6];
    const float* dir     = (const float*)d_in[7];
    const float* Fext    = (const float*)d_in[8];
    const float* bcd     = (const float*)d_in[9];
    const float* bcr     = (const float*)d_in[10];
    const long long* conn = (const long long*)d_in[11];

    int N = in_sizes[0] / 3;
    int E = in_sizes[3];
    int NB = (N + SPAN - 1) / SPAN;   // must be <= NBMAX

    // Workspace layout:
    //   0      accSlots   4096 B (64 slots * 64B)
    //   4096   cursors    NBMAX*CURP*4 = 65536 B (padded, one cursor/line)
    //   69632  base       (NBMAX+1)*4 B
    //   oFint  fp32/fp16 partial (K>1 only)
    //   oArena arena: 2*chunkElems records * 8 B (exact); the count-row
    //          matrix cntMat[CB][NBMAX] (384 KB) ALIASES the arena head —
    //          it is consumed by scan before fill writes the arena.
    size_t oCur   = 4096;
    size_t oBase  = oCur + (size_t)NBMAX * CURP * 4;          // 69632
    size_t oFint0 = align256(oBase + 4 * (NBMAX + 1));        // 73984
    size_t rowsBytes = (size_t)CB * NBMAX * 4;                // 393216

    const int cfgK[6] = {1, 2, 2, 4, 4, 8};
    const int cfgM[6] = {0, 1, 2, 1, 2, 2};
    int K = 8, mode = 2;
    size_t oF = oFint0, oA = oFint0;
    for (int t = 0; t < 6; ++t) {
        int Kc = cfgK[t], Mc = cfgM[t];
        size_t chunkE = (size_t)(E + Kc - 1) / Kc;
        size_t fsz = (Kc > 1) ? (size_t)3 * N * (Mc == 1 ? 4 : 2) : 0;
        size_t oAt = align256(oFint0 + fsz);
        size_t arenaB = 2 * chunkE * 8;
        if (arenaB < rowsBytes) arenaB = rowsBytes;   // alias safety for tiny E
        size_t need = oAt + arenaB;
        if (need <= ws_size || t == 5) {
            K = Kc; mode = Mc; oF = oFint0; oA = oAt;
            if (need <= ws_size) break;
        }
    }

    int chunkElems = (E + K - 1) / K;

    double*             accSlots = (double*)d_ws;
    int*                cursor   = (int*)((char*)d_ws + oCur);
    int*                base     = (int*)((char*)d_ws + oBase);
    float*              fint32   = (float*)((char*)d_ws + oF);
    __half*             fint16   = (__half*)((char*)d_ws + oF);
    uint2*              arena    = (uint2*)((char*)d_ws + oA);
    unsigned long long* arenaLL  = (unsigned long long*)arena;
    int*                rows     = (int*)arena;       // alias, pre-fill only

    for (int c = 0; c < K; ++c) {
        int cs = c * chunkElems;
        if (cs >= E) break;
        int ce = cs + chunkElems;
        if (ce > E) ce = E;
        int NT = (ce - cs + FBE - 1) / FBE;

        int isFirst = (c == 0);
        int isLast  = (ce == E);

        count_kernel<<<CB, 1024, 0, stream>>>(conn, rows, cs, ce);
        scan_kernel<<<1, 1024, 0, stream>>>(rows, cursor, base, accSlots, isFirst);
        fill_kernel<<<NT, FTH, 0, stream>>>(
            conn, pred, u_c, theta_c, len, pE, pA, pI, dir,
            arena, cursor, cs, ce);
        accum_kernel<<<NB, ATH, 0, stream>>>(
            arenaLL, base, Fext, bcd, bcr, accSlots,
            fint32, fint16, N, isFirst, isLast, mode);
    }

    final_kernel<<<1, 64, 0, stream>>>(accSlots, (float*)d_out);
}